// Round 1
// baseline (837.847 us; speedup 1.0000x reference)
//
#include <hip/hip_runtime.h>
#include <hip/hip_bf16.h>
#include <math.h>

typedef __bf16 bf16;
typedef bf16 bf16x4 __attribute__((ext_vector_type(4)));
typedef bf16 bf16x8 __attribute__((ext_vector_type(8)));
typedef float f32x4 __attribute__((ext_vector_type(4)));

#define T_TOK 4096
#define DDIM  768
#define HDIM  2688
#define NEXP  8
#define RMAX  9216   // max padded pair rows: 8192 + 8*127 -> round up

__device__ __forceinline__ void async_copy16(const void* g, void* l) {
    __builtin_amdgcn_global_load_lds(
        (__attribute__((address_space(1))) void*)g,
        (__attribute__((address_space(3))) void*)l,
        16, 0, 0);
}

// ---------------- Router: logits, top-2, weights, counts, z_loss ----------------
__global__ void router_kernel(const float* __restrict__ x,
                              const float* __restrict__ gate_w,
                              const float* __restrict__ ebias,
                              int* __restrict__ ctrl,          // [0..8) counts
                              int* __restrict__ tok_e,
                              float* __restrict__ tok_w,
                              float* __restrict__ zloss) {
    __shared__ float gw[NEXP * DDIM];
    int tid = threadIdx.x;
    for (int i = tid; i < NEXP * DDIM; i += 256) gw[i] = gate_w[i];
    __syncthreads();

    int wv = tid >> 6, lane = tid & 63;
    int t = blockIdx.x * 4 + wv;
    const float* xr = x + (size_t)t * DDIM;

    float xv[12];
#pragma unroll
    for (int j = 0; j < 12; ++j) xv[j] = xr[j * 64 + lane];

    float acc[NEXP];
#pragma unroll
    for (int e = 0; e < NEXP; ++e) {
        float a = 0.f;
#pragma unroll
        for (int j = 0; j < 12; ++j) a += xv[j] * gw[e * DDIM + j * 64 + lane];
        acc[e] = a;
    }
#pragma unroll
    for (int e = 0; e < NEXP; ++e) {
#pragma unroll
        for (int off = 32; off > 0; off >>= 1) acc[e] += __shfl_xor(acc[e], off);
    }

    if (lane == 0) {
        float b[NEXP];
#pragma unroll
        for (int e = 0; e < NEXP; ++e) b[e] = acc[e] + ebias[e];
        int i0 = 0;
#pragma unroll
        for (int e = 1; e < NEXP; ++e) if (b[e] > b[i0]) i0 = e;
        int i1 = (i0 == 0) ? 1 : 0;
        float b1 = b[i1];
#pragma unroll
        for (int e = 0; e < NEXP; ++e) if (e != i0 && b[e] > b1) { b1 = b[e]; i1 = e; }

        float l0 = acc[i0], l1 = acc[i1];
        float mx = fmaxf(l0, l1);
        float e0 = __expf(l0 - mx), e1 = __expf(l1 - mx);
        float inv = 1.f / (e0 + e1);
        tok_e[t * 2 + 0] = i0;
        tok_e[t * 2 + 1] = i1;
        tok_w[t * 2 + 0] = e0 * inv;
        tok_w[t * 2 + 1] = e1 * inv;
        atomicAdd(&ctrl[i0], 1);
        atomicAdd(&ctrl[i1], 1);

        float m8 = acc[0];
#pragma unroll
        for (int e = 1; e < NEXP; ++e) m8 = fmaxf(m8, acc[e]);
        float s = 0.f;
#pragma unroll
        for (int e = 0; e < NEXP; ++e) s += __expf(acc[e] - m8);
        float lse = m8 + __logf(s);
        atomicAdd(zloss, (1e-5f / (float)T_TOK) * lse * lse);
    }
}

// ---------------- 128-aligned exclusive prefix offsets ----------------
__global__ void offsets_kernel(int* ctrl) {
    if (threadIdx.x == 0 && blockIdx.x == 0) {
        int off = 0;
        for (int e = 0; e < NEXP; ++e) {
            ctrl[16 + e] = off;
            off += (ctrl[e] + 127) & ~127;
        }
        ctrl[16 + NEXP] = off;
    }
}

// ---------------- Scatter tokens into compact expert lists ----------------
__global__ void scatter_kernel(int* __restrict__ ctrl,
                               const int* __restrict__ tok_e,
                               const float* __restrict__ tok_w,
                               int* __restrict__ pair_tok,
                               float* __restrict__ pair_w) {
    int t = blockIdx.x * 256 + threadIdx.x;
    if (t >= T_TOK) return;
#pragma unroll
    for (int k = 0; k < 2; ++k) {
        int e = tok_e[t * 2 + k];
        int pos = ctrl[16 + e] + atomicAdd(&ctrl[8 + e], 1);
        pair_tok[pos] = t;
        pair_w[pos] = tok_w[t * 2 + k];
    }
}

// ---------------- Gather x rows -> bf16, zero-pad tail rows ----------------
__global__ void gather_kernel(const float* __restrict__ x,
                              const int* __restrict__ ctrl,
                              const int* __restrict__ pair_tok,
                              bf16* __restrict__ Xg) {
    int r = blockIdx.x;
    int tid = threadIdx.x;  // 192 threads, 4 floats each
    const int* offs = ctrl + 16;
    int total = offs[8];
    int tok = -1;
    if (r < total) {
        int e = 0;
#pragma unroll
        for (int i = 1; i < NEXP; ++i) if (r >= offs[i]) e = i;
        if (r - offs[e] < ctrl[e]) tok = pair_tok[r];
    }
    bf16x4 o;
    if (tok >= 0) {
        float4 v = *(const float4*)(x + (size_t)tok * DDIM + tid * 4);
        o.x = (bf16)v.x; o.y = (bf16)v.y; o.z = (bf16)v.z; o.w = (bf16)v.w;
    } else {
        o.x = (bf16)0.f; o.y = (bf16)0.f; o.z = (bf16)0.f; o.w = (bf16)0.f;
    }
    *(bf16x4*)(Xg + (size_t)r * DDIM + tid * 4) = o;
}

// ---------------- Transpose + fp32->bf16 convert of expert weights ----------------
// kind 0: w_gate [768,2688] -> WgT [2688,768]; kind 1: w_up likewise;
// kind 2: w_down [2688,768] -> WdT [768,2688]
__global__ void transpose_kernel(const float* __restrict__ wgp,
                                 const float* __restrict__ wup,
                                 const float* __restrict__ wdp,
                                 bf16* __restrict__ WgT,
                                 bf16* __restrict__ WuT,
                                 bf16* __restrict__ WdT) {
    __shared__ float tile[64][65];
    int m = blockIdx.y;
    int kind = m >> 3, e = m & 7;
    const float* src; bf16* dst; int R, C;
    if (kind == 0)      { src = wgp + (size_t)e * DDIM * HDIM; dst = WgT + (size_t)e * HDIM * DDIM; R = DDIM; C = HDIM; }
    else if (kind == 1) { src = wup + (size_t)e * DDIM * HDIM; dst = WuT + (size_t)e * HDIM * DDIM; R = DDIM; C = HDIM; }
    else                { src = wdp + (size_t)e * HDIM * DDIM; dst = WdT + (size_t)e * DDIM * HDIM; R = HDIM; C = DDIM; }

    int nR = R >> 6;
    int t = blockIdx.x;
    int tr = t % nR, tc = t / nR;
    int r0 = tr << 6, c0 = tc << 6;
    int lane = threadIdx.x & 63, wv = threadIdx.x >> 6;
#pragma unroll
    for (int rr = wv; rr < 64; rr += 4)
        tile[rr][lane] = src[(size_t)(r0 + rr) * C + c0 + lane];
    __syncthreads();
#pragma unroll
    for (int cc = wv; cc < 64; cc += 4)
        dst[(size_t)(c0 + cc) * R + r0 + lane] = (bf16)tile[lane][cc];
}

// ---------------- GEMM1: G = silu(Xg @ Wg) * (Xg @ Wu), per expert ----------------
// Block tile: 128 rows x 64 cols (for BOTH gate and up). BK=32.
__launch_bounds__(256)
__global__ void gemm1_kernel(const bf16* __restrict__ Xg,
                             const bf16* __restrict__ WgT,
                             const bf16* __restrict__ WuT,
                             const int* __restrict__ ctrl,
                             bf16* __restrict__ G) {
    int e = blockIdx.z;
    const int* offs = ctrl + 16;
    int off_e = offs[e];
    int pad_cnt = offs[e + 1] - off_e;
    int mtile = blockIdx.x;
    if (mtile * 128 >= pad_cnt) return;
    int n0 = blockIdx.y * 64;
    int row0 = off_e + mtile * 128;

    __shared__ __align__(16) bf16 sA[128 * 32];
    __shared__ __align__(16) bf16 sBg[64 * 32];
    __shared__ __align__(16) bf16 sBu[64 * 32];

    int tid = threadIdx.x;
    int wv = tid >> 6, lane = tid & 63;
    int wm = wv & 1, wn = wv >> 1;
    int quad = lane >> 4, lm = lane & 15;

    const bf16* Ab = Xg + (size_t)row0 * DDIM;
    const bf16* Bg = WgT + ((size_t)e * HDIM + n0) * DDIM;
    const bf16* Bu = WuT + ((size_t)e * HDIM + n0) * DDIM;

    f32x4 accg[4][2], accu[4][2];
#pragma unroll
    for (int mi = 0; mi < 4; ++mi)
#pragma unroll
        for (int ni = 0; ni < 2; ++ni) { accg[mi][ni] = 0.f; accu[mi][ni] = 0.f; }

    int arow = tid >> 2, aseg = tid & 3;
    for (int kk = 0; kk < DDIM; kk += 32) {
        async_copy16(Ab + (size_t)arow * DDIM + kk + aseg * 8, sA + (size_t)tid * 8);
        async_copy16(Ab + (size_t)(arow + 64) * DDIM + kk + aseg * 8, sA + (size_t)(tid + 256) * 8);
        async_copy16(Bg + (size_t)arow * DDIM + kk + aseg * 8, sBg + (size_t)tid * 8);
        async_copy16(Bu + (size_t)arow * DDIM + kk + aseg * 8, sBu + (size_t)tid * 8);
        __syncthreads();

        bf16x8 af[4], bg[2], bu[2];
#pragma unroll
        for (int mi = 0; mi < 4; ++mi)
            af[mi] = *(const bf16x8*)(sA + (wm * 64 + mi * 16 + lm) * 32 + quad * 8);
#pragma unroll
        for (int ni = 0; ni < 2; ++ni) {
            bg[ni] = *(const bf16x8*)(sBg + (wn * 32 + ni * 16 + lm) * 32 + quad * 8);
            bu[ni] = *(const bf16x8*)(sBu + (wn * 32 + ni * 16 + lm) * 32 + quad * 8);
        }
#pragma unroll
        for (int mi = 0; mi < 4; ++mi)
#pragma unroll
            for (int ni = 0; ni < 2; ++ni) {
                accg[mi][ni] = __builtin_amdgcn_mfma_f32_16x16x32_bf16(af[mi], bg[ni], accg[mi][ni], 0, 0, 0);
                accu[mi][ni] = __builtin_amdgcn_mfma_f32_16x16x32_bf16(af[mi], bu[ni], accu[mi][ni], 0, 0, 0);
            }
        __syncthreads();
    }

#pragma unroll
    for (int mi = 0; mi < 4; ++mi)
#pragma unroll
        for (int ni = 0; ni < 2; ++ni)
#pragma unroll
            for (int r = 0; r < 4; ++r) {
                float g = accg[mi][ni][r];
                float u = accu[mi][ni][r];
                float val = (g / (1.f + __expf(-g))) * u;   // silu(g) * u
                int rl = wm * 64 + mi * 16 + quad * 4 + r;
                int col = n0 + wn * 32 + ni * 16 + lm;
                G[(size_t)(row0 + rl) * HDIM + col] = (bf16)val;
            }
}

// ---------------- GEMM2: Y = G @ Wd; atomic weighted scatter into out ----------------
__launch_bounds__(256)
__global__ void gemm2_kernel(const bf16* __restrict__ G,
                             const bf16* __restrict__ WdT,
                             const int* __restrict__ ctrl,
                             const int* __restrict__ pair_tok,
                             const float* __restrict__ pair_w,
                             float* __restrict__ out) {
    int e = blockIdx.z;
    const int* offs = ctrl + 16;
    int off_e = offs[e];
    int cnt_e = ctrl[e];
    int pad_cnt = offs[e + 1] - off_e;
    int mtile = blockIdx.x;
    if (mtile * 128 >= pad_cnt) return;
    int n0 = blockIdx.y * 128;
    int row0 = off_e + mtile * 128;

    __shared__ __align__(16) bf16 sA[128 * 32];
    __shared__ __align__(16) bf16 sB[128 * 32];

    int tid = threadIdx.x;
    int wv = tid >> 6, lane = tid & 63;
    int wm = wv & 1, wn = wv >> 1;
    int quad = lane >> 4, lm = lane & 15;

    const bf16* Ab = G + (size_t)row0 * HDIM;
    const bf16* Bb = WdT + ((size_t)e * DDIM + n0) * HDIM;

    f32x4 acc[4][4];
#pragma unroll
    for (int mi = 0; mi < 4; ++mi)
#pragma unroll
        for (int ni = 0; ni < 4; ++ni) acc[mi][ni] = 0.f;

    int arow = tid >> 2, aseg = tid & 3;
    for (int kk = 0; kk < HDIM; kk += 32) {
        async_copy16(Ab + (size_t)arow * HDIM + kk + aseg * 8, sA + (size_t)tid * 8);
        async_copy16(Ab + (size_t)(arow + 64) * HDIM + kk + aseg * 8, sA + (size_t)(tid + 256) * 8);
        async_copy16(Bb + (size_t)arow * HDIM + kk + aseg * 8, sB + (size_t)tid * 8);
        async_copy16(Bb + (size_t)(arow + 64) * HDIM + kk + aseg * 8, sB + (size_t)(tid + 256) * 8);
        __syncthreads();

        bf16x8 af[4], bb[4];
#pragma unroll
        for (int mi = 0; mi < 4; ++mi)
            af[mi] = *(const bf16x8*)(sA + (wm * 64 + mi * 16 + lm) * 32 + quad * 8);
#pragma unroll
        for (int ni = 0; ni < 4; ++ni)
            bb[ni] = *(const bf16x8*)(sB + (wn * 64 + ni * 16 + lm) * 32 + quad * 8);
#pragma unroll
        for (int mi = 0; mi < 4; ++mi)
#pragma unroll
            for (int ni = 0; ni < 4; ++ni)
                acc[mi][ni] = __builtin_amdgcn_mfma_f32_16x16x32_bf16(af[mi], bb[ni], acc[mi][ni], 0, 0, 0);
        __syncthreads();
    }

#pragma unroll
    for (int mi = 0; mi < 4; ++mi)
#pragma unroll
        for (int r = 0; r < 4; ++r) {
            int rl = wm * 64 + mi * 16 + quad * 4 + r;
            if (mtile * 128 + rl < cnt_e) {
                int rabs = row0 + rl;
                int tok = pair_tok[rabs];
                float wt = pair_w[rabs];
#pragma unroll
                for (int ni = 0; ni < 4; ++ni) {
                    int col = n0 + wn * 64 + ni * 16 + lm;
                    atomicAdd(out + (size_t)tok * DDIM + col, wt * acc[mi][ni][r]);
                }
            }
        }
}

extern "C" void kernel_launch(void* const* d_in, const int* in_sizes, int n_in,
                              void* d_out, int out_size, void* d_ws, size_t ws_size,
                              hipStream_t stream) {
    const float* x      = (const float*)d_in[0];
    const float* gate_w = (const float*)d_in[1];
    const float* ebias  = (const float*)d_in[2];
    const float* wgp    = (const float*)d_in[3];
    const float* wup    = (const float*)d_in[4];
    const float* wdp    = (const float*)d_in[5];
    float* out = (float*)d_out;

    // workspace layout
    int*   ctrl     = (int*)d_ws;                       // 128 ints (counts[8], cursors[8], offs[9])
    int*   tok_e    = ctrl + 128;                       // 2*T ints
    float* tok_w    = (float*)(tok_e + 2 * T_TOK);      // 2*T floats
    int*   pair_tok = (int*)(tok_w + 2 * T_TOK);        // RMAX ints
    float* pair_w   = (float*)(pair_tok + RMAX);        // RMAX floats
    bf16*  Xg       = (bf16*)(pair_w + RMAX);           // RMAX*768
    bf16*  G        = Xg + (size_t)RMAX * DDIM;         // RMAX*2688
    bf16*  WgT      = G + (size_t)RMAX * HDIM;          // 8*2688*768
    bf16*  WuT      = WgT + (size_t)NEXP * DDIM * HDIM;
    bf16*  WdT      = WuT + (size_t)NEXP * DDIM * HDIM;

    hipMemsetAsync(d_out, 0, (size_t)(T_TOK * DDIM + 1) * sizeof(float), stream);
    hipMemsetAsync(d_ws, 0, 512, stream);

    router_kernel<<<T_TOK / 4, 256, 0, stream>>>(x, gate_w, ebias, ctrl, tok_e, tok_w,
                                                 out + (size_t)T_TOK * DDIM);
    offsets_kernel<<<1, 64, 0, stream>>>(ctrl);
    scatter_kernel<<<T_TOK / 256, 256, 0, stream>>>(ctrl, tok_e, tok_w, pair_tok, pair_w);
    transpose_kernel<<<dim3(504, 24), 256, 0, stream>>>(wgp, wup, wdp, WgT, WuT, WdT);
    gather_kernel<<<RMAX, 192, 0, stream>>>(x, ctrl, pair_tok, Xg);
    gemm1_kernel<<<dim3(32, HDIM / 64, NEXP), 256, 0, stream>>>(Xg, WgT, WuT, ctrl, G);
    gemm2_kernel<<<dim3(32, DDIM / 128, NEXP), 256, 0, stream>>>(G, WdT, ctrl, pair_tok, pair_w, out);
}

// Round 2
// 570.687 us; speedup vs baseline: 1.4681x; 1.4681x over previous
//
#include <hip/hip_runtime.h>
#include <hip/hip_bf16.h>
#include <math.h>

typedef __bf16 bf16;
typedef bf16 bf16x4 __attribute__((ext_vector_type(4)));
typedef bf16 bf16x8 __attribute__((ext_vector_type(8)));
typedef float f32x4 __attribute__((ext_vector_type(4)));

#define T_TOK 4096
#define DDIM  768
#define HDIM  2688
#define NEXP  8
#define RMAX  9216   // max padded pair rows
#define NG1   (NEXP * (HDIM / 64))   // 336 groups (divisible by 8)
#define MT1   32
#define NG2   (NEXP * (DDIM / 128))  // 48 groups (divisible by 8)
#define MT2   32

__device__ __forceinline__ void async_copy16(const void* g, void* l) {
    __builtin_amdgcn_global_load_lds(
        (__attribute__((address_space(1))) void*)g,
        (__attribute__((address_space(3))) void*)l,
        16, 0, 0);
}

// ---------------- Router: logits, top-2, weights, counts, z_loss ----------------
__global__ void router_kernel(const float* __restrict__ x,
                              const float* __restrict__ gate_w,
                              const float* __restrict__ ebias,
                              int* __restrict__ ctrl,
                              int* __restrict__ tok_e,
                              float* __restrict__ tok_w,
                              float* __restrict__ zloss) {
    __shared__ float gw[NEXP * DDIM];
    int tid = threadIdx.x;
    for (int i = tid; i < NEXP * DDIM; i += 256) gw[i] = gate_w[i];
    __syncthreads();

    int wv = tid >> 6, lane = tid & 63;
    int t = blockIdx.x * 4 + wv;
    const float* xr = x + (size_t)t * DDIM;

    float xv[12];
#pragma unroll
    for (int j = 0; j < 12; ++j) xv[j] = xr[j * 64 + lane];

    float acc[NEXP];
#pragma unroll
    for (int e = 0; e < NEXP; ++e) {
        float a = 0.f;
#pragma unroll
        for (int j = 0; j < 12; ++j) a += xv[j] * gw[e * DDIM + j * 64 + lane];
        acc[e] = a;
    }
#pragma unroll
    for (int e = 0; e < NEXP; ++e) {
#pragma unroll
        for (int off = 32; off > 0; off >>= 1) acc[e] += __shfl_xor(acc[e], off);
    }

    if (lane == 0) {
        float b[NEXP];
#pragma unroll
        for (int e = 0; e < NEXP; ++e) b[e] = acc[e] + ebias[e];
        int i0 = 0;
#pragma unroll
        for (int e = 1; e < NEXP; ++e) if (b[e] > b[i0]) i0 = e;
        int i1 = (i0 == 0) ? 1 : 0;
        float b1 = b[i1];
#pragma unroll
        for (int e = 0; e < NEXP; ++e) if (e != i0 && b[e] > b1) { b1 = b[e]; i1 = e; }

        float l0 = acc[i0], l1 = acc[i1];
        float mx = fmaxf(l0, l1);
        float e0 = __expf(l0 - mx), e1 = __expf(l1 - mx);
        float inv = 1.f / (e0 + e1);
        tok_e[t * 2 + 0] = i0;
        tok_e[t * 2 + 1] = i1;
        tok_w[t * 2 + 0] = e0 * inv;
        tok_w[t * 2 + 1] = e1 * inv;
        atomicAdd(&ctrl[i0], 1);
        atomicAdd(&ctrl[i1], 1);

        float m8 = acc[0];
#pragma unroll
        for (int e = 1; e < NEXP; ++e) m8 = fmaxf(m8, acc[e]);
        float s = 0.f;
#pragma unroll
        for (int e = 0; e < NEXP; ++e) s += __expf(acc[e] - m8);
        float lse = m8 + __logf(s);
        atomicAdd(zloss, (1e-5f / (float)T_TOK) * lse * lse);
    }
}

__global__ void offsets_kernel(int* ctrl) {
    if (threadIdx.x == 0 && blockIdx.x == 0) {
        int off = 0;
        for (int e = 0; e < NEXP; ++e) {
            ctrl[16 + e] = off;
            off += (ctrl[e] + 127) & ~127;
        }
        ctrl[16 + NEXP] = off;
    }
}

__global__ void scatter_kernel(int* __restrict__ ctrl,
                               const int* __restrict__ tok_e,
                               const float* __restrict__ tok_w,
                               int* __restrict__ pair_tok,
                               float* __restrict__ pair_w) {
    int t = blockIdx.x * 256 + threadIdx.x;
    if (t >= T_TOK) return;
#pragma unroll
    for (int k = 0; k < 2; ++k) {
        int e = tok_e[t * 2 + k];
        int pos = ctrl[16 + e] + atomicAdd(&ctrl[8 + e], 1);
        pair_tok[pos] = t;
        pair_w[pos] = tok_w[t * 2 + k];
    }
}

__global__ void gather_kernel(const float* __restrict__ x,
                              const int* __restrict__ ctrl,
                              const int* __restrict__ pair_tok,
                              bf16* __restrict__ Xg) {
    int r = blockIdx.x;
    int tid = threadIdx.x;  // 192 threads, 4 floats each
    const int* offs = ctrl + 16;
    int total = offs[8];
    int tok = -1;
    if (r < total) {
        int e = 0;
#pragma unroll
        for (int i = 1; i < NEXP; ++i) if (r >= offs[i]) e = i;
        if (r - offs[e] < ctrl[e]) tok = pair_tok[r];
    }
    bf16x4 o;
    if (tok >= 0) {
        float4 v = *(const float4*)(x + (size_t)tok * DDIM + tid * 4);
        o.x = (bf16)v.x; o.y = (bf16)v.y; o.z = (bf16)v.z; o.w = (bf16)v.w;
    } else {
        o.x = (bf16)0.f; o.y = (bf16)0.f; o.z = (bf16)0.f; o.w = (bf16)0.f;
    }
    *(bf16x4*)(Xg + (size_t)r * DDIM + tid * 4) = o;
}

__global__ void transpose_kernel(const float* __restrict__ wgp,
                                 const float* __restrict__ wup,
                                 const float* __restrict__ wdp,
                                 bf16* __restrict__ WgT,
                                 bf16* __restrict__ WuT,
                                 bf16* __restrict__ WdT) {
    __shared__ float tile[64][65];
    int m = blockIdx.y;
    int kind = m >> 3, e = m & 7;
    const float* src; bf16* dst; int R, C;
    if (kind == 0)      { src = wgp + (size_t)e * DDIM * HDIM; dst = WgT + (size_t)e * HDIM * DDIM; R = DDIM; C = HDIM; }
    else if (kind == 1) { src = wup + (size_t)e * DDIM * HDIM; dst = WuT + (size_t)e * HDIM * DDIM; R = DDIM; C = HDIM; }
    else                { src = wdp + (size_t)e * HDIM * DDIM; dst = WdT + (size_t)e * DDIM * HDIM; R = HDIM; C = DDIM; }

    int nR = R >> 6;
    int t = blockIdx.x;
    int tr = t % nR, tc = t / nR;
    int r0 = tr << 6, c0 = tc << 6;
    int lane = threadIdx.x & 63, wv = threadIdx.x >> 6;
#pragma unroll
    for (int rr = wv; rr < 64; rr += 4)
        tile[rr][lane] = src[(size_t)(r0 + rr) * C + c0 + lane];
    __syncthreads();
#pragma unroll
    for (int cc = wv; cc < 64; cc += 4)
        dst[(size_t)(c0 + cc) * R + r0 + lane] = (bf16)tile[lane][cc];
}

// ---------------- GEMM1: G = silu(Xg @ Wg) * (Xg @ Wu), per expert ----------------
// 128 rows x 64 cols (both gate & up), BK=32, double-buffered LDS,
// XCD-swizzled 1D grid: id = g + mtile*NG1, e = g%8 -> expert pinned to XCD.
__launch_bounds__(256)
__global__ void gemm1_kernel(const bf16* __restrict__ Xg,
                             const bf16* __restrict__ WgT,
                             const bf16* __restrict__ WuT,
                             const int* __restrict__ ctrl,
                             bf16* __restrict__ G) {
    int id = blockIdx.x;
    int g = id % NG1;
    int mtile = id / NG1;
    int e = g & 7;
    int ntile = g >> 3;

    const int* offs = ctrl + 16;
    int off_e = offs[e];
    int pad_cnt = offs[e + 1] - off_e;
    if (mtile * 128 >= pad_cnt) return;
    int n0 = ntile * 64;
    int row0 = off_e + mtile * 128;

    __shared__ __align__(16) bf16 sA[2][128 * 32];
    __shared__ __align__(16) bf16 sBg[2][64 * 32];
    __shared__ __align__(16) bf16 sBu[2][64 * 32];

    int tid = threadIdx.x;
    int wv = tid >> 6, lane = tid & 63;
    int wm = wv & 1, wn = wv >> 1;
    int quad = lane >> 4, lm = lane & 15;

    const bf16* Ab = Xg + (size_t)row0 * DDIM;
    const bf16* Bg = WgT + ((size_t)e * HDIM + n0) * DDIM;
    const bf16* Bu = WuT + ((size_t)e * HDIM + n0) * DDIM;

    f32x4 accg[4][2], accu[4][2];
#pragma unroll
    for (int mi = 0; mi < 4; ++mi)
#pragma unroll
        for (int ni = 0; ni < 2; ++ni) { accg[mi][ni] = 0.f; accu[mi][ni] = 0.f; }

    int arow = tid >> 2, aseg = tid & 3;
    size_t aoff = (size_t)arow * DDIM + aseg * 8;

    auto stage = [&](int buf, int kk) {
        async_copy16(Ab + aoff + kk, &sA[buf][tid * 8]);
        async_copy16(Ab + aoff + (size_t)64 * DDIM + kk, &sA[buf][(tid + 256) * 8]);
        async_copy16(Bg + aoff + kk, &sBg[buf][tid * 8]);
        async_copy16(Bu + aoff + kk, &sBu[buf][tid * 8]);
    };

    stage(0, 0);
    const int NK = DDIM / 32;
    for (int ks = 0; ks < NK; ++ks) {
        __syncthreads();                       // drains vmcnt(0): buf[ks&1] ready
        if (ks + 1 < NK) stage((ks + 1) & 1, (ks + 1) * 32);
        int buf = ks & 1;

        bf16x8 af[4], bg[2], bu[2];
#pragma unroll
        for (int mi = 0; mi < 4; ++mi)
            af[mi] = *(const bf16x8*)(&sA[buf][(wm * 64 + mi * 16 + lm) * 32 + quad * 8]);
#pragma unroll
        for (int ni = 0; ni < 2; ++ni) {
            bg[ni] = *(const bf16x8*)(&sBg[buf][(wn * 32 + ni * 16 + lm) * 32 + quad * 8]);
            bu[ni] = *(const bf16x8*)(&sBu[buf][(wn * 32 + ni * 16 + lm) * 32 + quad * 8]);
        }
#pragma unroll
        for (int mi = 0; mi < 4; ++mi)
#pragma unroll
            for (int ni = 0; ni < 2; ++ni) {
                accg[mi][ni] = __builtin_amdgcn_mfma_f32_16x16x32_bf16(af[mi], bg[ni], accg[mi][ni], 0, 0, 0);
                accu[mi][ni] = __builtin_amdgcn_mfma_f32_16x16x32_bf16(af[mi], bu[ni], accu[mi][ni], 0, 0, 0);
            }
    }

#pragma unroll
    for (int mi = 0; mi < 4; ++mi)
#pragma unroll
        for (int ni = 0; ni < 2; ++ni)
#pragma unroll
            for (int r = 0; r < 4; ++r) {
                float gg = accg[mi][ni][r];
                float u = accu[mi][ni][r];
                float val = (gg / (1.f + __expf(-gg))) * u;   // silu(g) * u
                int rl = wm * 64 + mi * 16 + quad * 4 + r;
                int col = n0 + wn * 32 + ni * 16 + lm;
                G[(size_t)(row0 + rl) * HDIM + col] = (bf16)val;
            }
}

// ---------------- GEMM2: Y = G @ Wd; atomic weighted scatter into out ----------------
__launch_bounds__(256)
__global__ void gemm2_kernel(const bf16* __restrict__ G,
                             const bf16* __restrict__ WdT,
                             const int* __restrict__ ctrl,
                             const int* __restrict__ pair_tok,
                             const float* __restrict__ pair_w,
                             float* __restrict__ out) {
    int id = blockIdx.x;
    int g = id % NG2;
    int mtile = id / NG2;
    int e = g & 7;
    int ntile = g >> 3;

    const int* offs = ctrl + 16;
    int off_e = offs[e];
    int cnt_e = ctrl[e];
    int pad_cnt = offs[e + 1] - off_e;
    if (mtile * 128 >= pad_cnt) return;
    int n0 = ntile * 128;
    int row0 = off_e + mtile * 128;

    __shared__ __align__(16) bf16 sA[2][128 * 32];
    __shared__ __align__(16) bf16 sB[2][128 * 32];

    int tid = threadIdx.x;
    int wv = tid >> 6, lane = tid & 63;
    int wm = wv & 1, wn = wv >> 1;
    int quad = lane >> 4, lm = lane & 15;

    const bf16* Ab = G + (size_t)row0 * HDIM;
    const bf16* Bb = WdT + ((size_t)e * DDIM + n0) * HDIM;

    f32x4 acc[4][4];
#pragma unroll
    for (int mi = 0; mi < 4; ++mi)
#pragma unroll
        for (int ni = 0; ni < 4; ++ni) acc[mi][ni] = 0.f;

    int arow = tid >> 2, aseg = tid & 3;
    size_t aoff = (size_t)arow * HDIM + aseg * 8;

    auto stage = [&](int buf, int kk) {
        async_copy16(Ab + aoff + kk, &sA[buf][tid * 8]);
        async_copy16(Ab + aoff + (size_t)64 * HDIM + kk, &sA[buf][(tid + 256) * 8]);
        async_copy16(Bb + aoff + kk, &sB[buf][tid * 8]);
        async_copy16(Bb + aoff + (size_t)64 * HDIM + kk, &sB[buf][(tid + 256) * 8]);
    };

    stage(0, 0);
    const int NK = HDIM / 32;
    for (int ks = 0; ks < NK; ++ks) {
        __syncthreads();
        if (ks + 1 < NK) stage((ks + 1) & 1, (ks + 1) * 32);
        int buf = ks & 1;

        bf16x8 af[4], bb[4];
#pragma unroll
        for (int mi = 0; mi < 4; ++mi)
            af[mi] = *(const bf16x8*)(&sA[buf][(wm * 64 + mi * 16 + lm) * 32 + quad * 8]);
#pragma unroll
        for (int ni = 0; ni < 4; ++ni)
            bb[ni] = *(const bf16x8*)(&sB[buf][(wn * 64 + ni * 16 + lm) * 32 + quad * 8]);
#pragma unroll
        for (int mi = 0; mi < 4; ++mi)
#pragma unroll
            for (int ni = 0; ni < 4; ++ni)
                acc[mi][ni] = __builtin_amdgcn_mfma_f32_16x16x32_bf16(af[mi], bb[ni], acc[mi][ni], 0, 0, 0);
    }

#pragma unroll
    for (int mi = 0; mi < 4; ++mi)
#pragma unroll
        for (int r = 0; r < 4; ++r) {
            int rl = wm * 64 + mi * 16 + quad * 4 + r;
            if (mtile * 128 + rl < cnt_e) {
                int rabs = row0 + rl;
                int tok = pair_tok[rabs];
                float wt = pair_w[rabs];
#pragma unroll
                for (int ni = 0; ni < 4; ++ni) {
                    int col = n0 + wn * 64 + ni * 16 + lm;
                    atomicAdd(out + (size_t)tok * DDIM + col, wt * acc[mi][ni][r]);
                }
            }
        }
}

extern "C" void kernel_launch(void* const* d_in, const int* in_sizes, int n_in,
                              void* d_out, int out_size, void* d_ws, size_t ws_size,
                              hipStream_t stream) {
    const float* x      = (const float*)d_in[0];
    const float* gate_w = (const float*)d_in[1];
    const float* ebias  = (const float*)d_in[2];
    const float* wgp    = (const float*)d_in[3];
    const float* wup    = (const float*)d_in[4];
    const float* wdp    = (const float*)d_in[5];
    float* out = (float*)d_out;

    int*   ctrl     = (int*)d_ws;
    int*   tok_e    = ctrl + 128;
    float* tok_w    = (float*)(tok_e + 2 * T_TOK);
    int*   pair_tok = (int*)(tok_w + 2 * T_TOK);
    float* pair_w   = (float*)(pair_tok + RMAX);
    bf16*  Xg       = (bf16*)(pair_w + RMAX);
    bf16*  G        = Xg + (size_t)RMAX * DDIM;
    bf16*  WgT      = G + (size_t)RMAX * HDIM;
    bf16*  WuT      = WgT + (size_t)NEXP * DDIM * HDIM;
    bf16*  WdT      = WuT + (size_t)NEXP * DDIM * HDIM;

    hipMemsetAsync(d_out, 0, (size_t)(T_TOK * DDIM + 1) * sizeof(float), stream);
    hipMemsetAsync(d_ws, 0, 512, stream);

    router_kernel<<<T_TOK / 4, 256, 0, stream>>>(x, gate_w, ebias, ctrl, tok_e, tok_w,
                                                 out + (size_t)T_TOK * DDIM);
    offsets_kernel<<<1, 64, 0, stream>>>(ctrl);
    scatter_kernel<<<T_TOK / 256, 256, 0, stream>>>(ctrl, tok_e, tok_w, pair_tok, pair_w);
    transpose_kernel<<<dim3(504, 24), 256, 0, stream>>>(wgp, wup, wdp, WgT, WuT, WdT);
    gather_kernel<<<RMAX, 192, 0, stream>>>(x, ctrl, pair_tok, Xg);
    gemm1_kernel<<<NG1 * MT1, 256, 0, stream>>>(Xg, WgT, WuT, ctrl, G);
    gemm2_kernel<<<NG2 * MT2, 256, 0, stream>>>(G, WdT, ctrl, pair_tok, pair_w, out);
}

// Round 3
// 539.115 us; speedup vs baseline: 1.5541x; 1.0586x over previous
//
#include <hip/hip_runtime.h>
#include <hip/hip_bf16.h>
#include <math.h>

typedef __bf16 bf16;
typedef bf16 bf16x2 __attribute__((ext_vector_type(2)));
typedef bf16 bf16x4 __attribute__((ext_vector_type(4)));
typedef bf16 bf16x8 __attribute__((ext_vector_type(8)));
typedef float f32x4 __attribute__((ext_vector_type(4)));

#define T_TOK 4096
#define DDIM  768
#define HDIM  2688
#define NEXP  8
#define RMAX  9216            // max padded pair rows (8192 + 8*127 rounded up)
#define NMT   (RMAX / 128)    // 72 max mtiles
#define NT1   (HDIM / 64)     // 42
#define NT2   (DDIM / 128)    // 6
#define KHALF (HDIM / 2)      // 1344

__device__ __forceinline__ void async_copy16(const void* g, void* l) {
    __builtin_amdgcn_global_load_lds(
        (__attribute__((address_space(1))) void*)g,
        (__attribute__((address_space(3))) void*)l,
        16, 0, 0);
}

// ---------------- Router ----------------
__global__ void router_kernel(const float* __restrict__ x,
                              const float* __restrict__ gate_w,
                              const float* __restrict__ ebias,
                              int* __restrict__ ctrl,
                              int* __restrict__ tok_e,
                              float* __restrict__ tok_w,
                              float* __restrict__ zloss) {
    __shared__ float gw[NEXP * DDIM];
    int tid = threadIdx.x;
    for (int i = tid; i < NEXP * DDIM; i += 256) gw[i] = gate_w[i];
    __syncthreads();

    int wv = tid >> 6, lane = tid & 63;
    int t = blockIdx.x * 4 + wv;
    const float* xr = x + (size_t)t * DDIM;

    float xv[12];
#pragma unroll
    for (int j = 0; j < 12; ++j) xv[j] = xr[j * 64 + lane];

    float acc[NEXP];
#pragma unroll
    for (int e = 0; e < NEXP; ++e) {
        float a = 0.f;
#pragma unroll
        for (int j = 0; j < 12; ++j) a += xv[j] * gw[e * DDIM + j * 64 + lane];
        acc[e] = a;
    }
#pragma unroll
    for (int e = 0; e < NEXP; ++e) {
#pragma unroll
        for (int off = 32; off > 0; off >>= 1) acc[e] += __shfl_xor(acc[e], off);
    }

    if (lane == 0) {
        float b[NEXP];
#pragma unroll
        for (int e = 0; e < NEXP; ++e) b[e] = acc[e] + ebias[e];
        int i0 = 0;
#pragma unroll
        for (int e = 1; e < NEXP; ++e) if (b[e] > b[i0]) i0 = e;
        int i1 = (i0 == 0) ? 1 : 0;
        float b1 = b[i1];
#pragma unroll
        for (int e = 0; e < NEXP; ++e) if (e != i0 && b[e] > b1) { b1 = b[e]; i1 = e; }

        float l0 = acc[i0], l1 = acc[i1];
        float mx = fmaxf(l0, l1);
        float e0 = __expf(l0 - mx), e1 = __expf(l1 - mx);
        float inv = 1.f / (e0 + e1);
        tok_e[t * 2 + 0] = i0;
        tok_e[t * 2 + 1] = i1;
        tok_w[t * 2 + 0] = e0 * inv;
        tok_w[t * 2 + 1] = e1 * inv;
        atomicAdd(&ctrl[i0], 1);
        atomicAdd(&ctrl[i1], 1);

        float m8 = acc[0];
#pragma unroll
        for (int e = 1; e < NEXP; ++e) m8 = fmaxf(m8, acc[e]);
        float s = 0.f;
#pragma unroll
        for (int e = 0; e < NEXP; ++e) s += __expf(acc[e] - m8);
        float lse = m8 + __logf(s);
        atomicAdd(zloss, (1e-5f / (float)T_TOK) * lse * lse);
    }
}

__global__ void offsets_kernel(int* ctrl) {
    if (threadIdx.x == 0 && blockIdx.x == 0) {
        int off = 0;
        for (int e = 0; e < NEXP; ++e) {
            ctrl[16 + e] = off;
            off += (ctrl[e] + 127) & ~127;
        }
        ctrl[16 + NEXP] = off;
    }
}

__global__ void scatter_kernel(int* __restrict__ ctrl,
                               const int* __restrict__ tok_e,
                               const float* __restrict__ tok_w,
                               int* __restrict__ pair_tok,
                               int* __restrict__ tok_pos) {
    int t = blockIdx.x * 256 + threadIdx.x;
    if (t >= T_TOK) return;
#pragma unroll
    for (int k = 0; k < 2; ++k) {
        int e = tok_e[t * 2 + k];
        int pos = ctrl[16 + e] + atomicAdd(&ctrl[8 + e], 1);
        pair_tok[pos] = t;
        tok_pos[t * 2 + k] = pos;
    }
}

__global__ void gather_kernel(const float* __restrict__ x,
                              const int* __restrict__ ctrl,
                              const int* __restrict__ pair_tok,
                              bf16* __restrict__ Xg) {
    int r = blockIdx.x;
    int tid = threadIdx.x;  // 192 threads, 4 floats each
    const int* offs = ctrl + 16;
    int total = offs[8];
    int tok = -1;
    if (r < total) {
        int e = 0;
#pragma unroll
        for (int i = 1; i < NEXP; ++i) if (r >= offs[i]) e = i;
        if (r - offs[e] < ctrl[e]) tok = pair_tok[r];
    }
    bf16x4 o;
    if (tok >= 0) {
        float4 v = *(const float4*)(x + (size_t)tok * DDIM + tid * 4);
        o.x = (bf16)v.x; o.y = (bf16)v.y; o.z = (bf16)v.z; o.w = (bf16)v.w;
    } else {
        o.x = (bf16)0.f; o.y = (bf16)0.f; o.z = (bf16)0.f; o.w = (bf16)0.f;
    }
    *(bf16x4*)(Xg + (size_t)r * DDIM + tid * 4) = o;
}

// ---------------- Weight transpose fp32->bf16 ----------------
__global__ void transpose_kernel(const float* __restrict__ wgp,
                                 const float* __restrict__ wup,
                                 const float* __restrict__ wdp,
                                 bf16* __restrict__ WgT,
                                 bf16* __restrict__ WuT,
                                 bf16* __restrict__ WdT) {
    __shared__ float tile[64][65];
    int m = blockIdx.y;
    int kind = m >> 3, e = m & 7;
    const float* src; bf16* dst; int R, C;
    if (kind == 0)      { src = wgp + (size_t)e * DDIM * HDIM; dst = WgT + (size_t)e * HDIM * DDIM; R = DDIM; C = HDIM; }
    else if (kind == 1) { src = wup + (size_t)e * DDIM * HDIM; dst = WuT + (size_t)e * HDIM * DDIM; R = DDIM; C = HDIM; }
    else                { src = wdp + (size_t)e * HDIM * DDIM; dst = WdT + (size_t)e * DDIM * HDIM; R = HDIM; C = DDIM; }

    int nR = R >> 6;
    int t = blockIdx.x;
    int tr = t % nR, tc = t / nR;
    int r0 = tr << 6, c0 = tc << 6;
    int lane = threadIdx.x & 63, wv = threadIdx.x >> 6;
#pragma unroll
    for (int rr = wv; rr < 64; rr += 4)
        tile[rr][lane] = src[(size_t)(r0 + rr) * C + c0 + lane];
    __syncthreads();
    int half = lane >> 5, rp = (lane & 31) * 2;
#pragma unroll
    for (int cc0 = wv * 2; cc0 < 64; cc0 += 8) {
        int cc = cc0 + half;
        bf16x2 v;
        v.x = (bf16)tile[rp][cc];
        v.y = (bf16)tile[rp + 1][cc];
        *(bf16x2*)(dst + (size_t)(c0 + cc) * R + r0 + rp) = v;
    }
}

// ---------------- GEMM1: G = silu(Xg@Wg) * (Xg@Wu) ----------------
// grid: gm*NT1 + nt; tile 128 rows x 64 cols (gate & up); BK=32, dbuf, swizzled LDS.
__launch_bounds__(256)
__global__ void gemm1_kernel(const bf16* __restrict__ Xg,
                             const bf16* __restrict__ WgT,
                             const bf16* __restrict__ WuT,
                             const int* __restrict__ ctrl,
                             bf16* __restrict__ G) {
    int id = blockIdx.x;
    int gm = id / NT1, nt = id % NT1;
    const int* offs = ctrl + 16;
    int row0 = gm * 128;
    if (row0 >= offs[NEXP]) return;
    int e = 0;
#pragma unroll
    for (int i = 1; i < NEXP; ++i) if (row0 >= offs[i]) e = i;
    int n0 = nt * 64;

    __shared__ __align__(16) bf16 sA[2][128 * 32];
    __shared__ __align__(16) bf16 sBg[2][64 * 32];
    __shared__ __align__(16) bf16 sBu[2][64 * 32];

    int tid = threadIdx.x;
    int wv = tid >> 6, lane = tid & 63;
    int wm = wv & 1, wn = wv >> 1;
    int quad = lane >> 4, lm = lane & 15;

    // staging: lane (arow, aseg) sources swizzled k-chunk aseg^((arow>>1)&3)
    int arow = tid >> 2, aseg = tid & 3;
    int kc = (aseg ^ ((arow >> 1) & 3)) * 8;
    size_t aoff = (size_t)arow * DDIM + kc;

    const bf16* Ab = Xg + (size_t)row0 * DDIM + aoff;
    const bf16* A2 = Ab + (size_t)64 * DDIM;
    const bf16* Bg = WgT + ((size_t)e * HDIM + n0) * DDIM + aoff;
    const bf16* Bu = WuT + ((size_t)e * HDIM + n0) * DDIM + aoff;

    bf16* dA  = &sA[0][0] + (size_t)tid * 8;
    bf16* dA2 = dA + 256 * 8;
    bf16* dBg = &sBg[0][0] + (size_t)tid * 8;
    bf16* dBu = &sBu[0][0] + (size_t)tid * 8;

    // fragment read bases (swizzled): row stride 32 elts, chunk quad^((lm>>1)&3)
    int swq = quad ^ ((lm >> 1) & 3);
    const bf16* fa = &sA[0][0] + (wm * 64 + lm) * 32 + swq * 8;
    const bf16* fg = &sBg[0][0] + (wn * 32 + lm) * 32 + swq * 8;
    const bf16* fu = &sBu[0][0] + (wn * 32 + lm) * 32 + swq * 8;

    f32x4 accg[4][2], accu[4][2];
#pragma unroll
    for (int mi = 0; mi < 4; ++mi)
#pragma unroll
        for (int ni = 0; ni < 2; ++ni) { accg[mi][ni] = 0.f; accu[mi][ni] = 0.f; }

    // prologue stage into buf 0
    async_copy16(Ab, dA);
    async_copy16(A2, dA2);
    async_copy16(Bg, dBg);
    async_copy16(Bu, dBu);

    const int NK = DDIM / 32;  // 24
#pragma unroll
    for (int ks = 0; ks < NK; ++ks) {
        __syncthreads();
        if (ks + 1 < NK) {
            int kk = (ks + 1) * 32;
            int bo = ((ks + 1) & 1) ? 1 : 0;
            async_copy16(Ab + kk, dA + bo * 128 * 32);
            async_copy16(A2 + kk, dA2 + bo * 128 * 32);
            async_copy16(Bg + kk, dBg + bo * 64 * 32);
            async_copy16(Bu + kk, dBu + bo * 64 * 32);
        }
        int buf = ks & 1;
        bf16x8 af[4], bg[2], bu[2];
#pragma unroll
        for (int mi = 0; mi < 4; ++mi)
            af[mi] = *(const bf16x8*)(fa + buf * 128 * 32 + mi * 16 * 32);
#pragma unroll
        for (int ni = 0; ni < 2; ++ni) {
            bg[ni] = *(const bf16x8*)(fg + buf * 64 * 32 + ni * 16 * 32);
            bu[ni] = *(const bf16x8*)(fu + buf * 64 * 32 + ni * 16 * 32);
        }
#pragma unroll
        for (int mi = 0; mi < 4; ++mi)
#pragma unroll
            for (int ni = 0; ni < 2; ++ni) {
                accg[mi][ni] = __builtin_amdgcn_mfma_f32_16x16x32_bf16(af[mi], bg[ni], accg[mi][ni], 0, 0, 0);
                accu[mi][ni] = __builtin_amdgcn_mfma_f32_16x16x32_bf16(af[mi], bu[ni], accu[mi][ni], 0, 0, 0);
            }
    }

#pragma unroll
    for (int mi = 0; mi < 4; ++mi)
#pragma unroll
        for (int ni = 0; ni < 2; ++ni)
#pragma unroll
            for (int r = 0; r < 4; ++r) {
                float gg = accg[mi][ni][r];
                float u = accu[mi][ni][r];
                float val = (gg / (1.f + __expf(-gg))) * u;
                int rl = wm * 64 + mi * 16 + quad * 4 + r;
                int col = n0 + wn * 32 + ni * 16 + lm;
                G[(size_t)(row0 + rl) * HDIM + col] = (bf16)val;
            }
}

// ---------------- GEMM2: Y_s = G[:, s*1344:(s+1)*1344] @ Wd[s half], bf16 partials ----------------
__launch_bounds__(256)
__global__ void gemm2_kernel(const bf16* __restrict__ G,
                             const bf16* __restrict__ WdT,
                             const int* __restrict__ ctrl,
                             bf16* __restrict__ Ya,
                             bf16* __restrict__ Yb) {
    int id = blockIdx.x;
    int gm = id / (NT2 * 2);
    int r2 = id % (NT2 * 2);
    int nt = r2 >> 1, s = r2 & 1;
    const int* offs = ctrl + 16;
    int row0 = gm * 128;
    if (row0 >= offs[NEXP]) return;
    int e = 0;
#pragma unroll
    for (int i = 1; i < NEXP; ++i) if (row0 >= offs[i]) e = i;
    int n0 = nt * 128;

    __shared__ __align__(16) bf16 sA[2][128 * 32];
    __shared__ __align__(16) bf16 sB[2][128 * 32];

    int tid = threadIdx.x;
    int wv = tid >> 6, lane = tid & 63;
    int wm = wv & 1, wn = wv >> 1;
    int quad = lane >> 4, lm = lane & 15;

    int arow = tid >> 2, aseg = tid & 3;
    int kc = (aseg ^ ((arow >> 1) & 3)) * 8;
    size_t aoff = (size_t)arow * HDIM + kc + s * KHALF;

    const bf16* Ab = G + (size_t)row0 * HDIM + aoff;
    const bf16* A2 = Ab + (size_t)64 * HDIM;
    const bf16* Bb = WdT + ((size_t)e * DDIM + n0) * HDIM + aoff;
    const bf16* B2 = Bb + (size_t)64 * HDIM;

    bf16* dA  = &sA[0][0] + (size_t)tid * 8;
    bf16* dA2 = dA + 256 * 8;
    bf16* dB  = &sB[0][0] + (size_t)tid * 8;
    bf16* dB2 = dB + 256 * 8;

    int swq = quad ^ ((lm >> 1) & 3);
    const bf16* fa = &sA[0][0] + (wm * 64 + lm) * 32 + swq * 8;
    const bf16* fb = &sB[0][0] + (wn * 64 + lm) * 32 + swq * 8;

    f32x4 acc[4][4];
#pragma unroll
    for (int mi = 0; mi < 4; ++mi)
#pragma unroll
        for (int ni = 0; ni < 4; ++ni) acc[mi][ni] = 0.f;

    async_copy16(Ab, dA);
    async_copy16(A2, dA2);
    async_copy16(Bb, dB);
    async_copy16(B2, dB2);

    const int NK = KHALF / 32;  // 42
#pragma unroll
    for (int ks = 0; ks < NK; ++ks) {
        __syncthreads();
        if (ks + 1 < NK) {
            int kk = (ks + 1) * 32;
            int bo = ((ks + 1) & 1) ? 1 : 0;
            async_copy16(Ab + kk, dA + bo * 128 * 32);
            async_copy16(A2 + kk, dA2 + bo * 128 * 32);
            async_copy16(Bb + kk, dB + bo * 128 * 32);
            async_copy16(B2 + kk, dB2 + bo * 128 * 32);
        }
        int buf = ks & 1;
        bf16x8 af[4], bb[4];
#pragma unroll
        for (int mi = 0; mi < 4; ++mi)
            af[mi] = *(const bf16x8*)(fa + buf * 128 * 32 + mi * 16 * 32);
#pragma unroll
        for (int ni = 0; ni < 4; ++ni)
            bb[ni] = *(const bf16x8*)(fb + buf * 128 * 32 + ni * 16 * 32);
#pragma unroll
        for (int mi = 0; mi < 4; ++mi)
#pragma unroll
            for (int ni = 0; ni < 4; ++ni)
                acc[mi][ni] = __builtin_amdgcn_mfma_f32_16x16x32_bf16(af[mi], bb[ni], acc[mi][ni], 0, 0, 0);
    }

    bf16* Y = s ? Yb : Ya;
#pragma unroll
    for (int mi = 0; mi < 4; ++mi)
#pragma unroll
        for (int r = 0; r < 4; ++r) {
            int rl = wm * 64 + mi * 16 + quad * 4 + r;
#pragma unroll
            for (int ni = 0; ni < 4; ++ni) {
                int col = n0 + wn * 64 + ni * 16 + lm;
                Y[(size_t)(row0 + rl) * DDIM + col] = (bf16)acc[mi][ni][r];
            }
        }
}

// ---------------- Combine: out[t] = w0*(Ya[p0]+Yb[p0]) + w1*(Ya[p1]+Yb[p1]) ----------------
__global__ void combine_kernel(const bf16* __restrict__ Ya,
                               const bf16* __restrict__ Yb,
                               const int* __restrict__ tok_pos,
                               const float* __restrict__ tok_w,
                               float* __restrict__ out) {
    int t = blockIdx.x;
    int i = threadIdx.x;           // 192 threads x 4 cols
    int p0 = tok_pos[t * 2 + 0], p1 = tok_pos[t * 2 + 1];
    float w0 = tok_w[t * 2 + 0], w1 = tok_w[t * 2 + 1];
    bf16x4 a0 = *(const bf16x4*)(Ya + (size_t)p0 * DDIM + i * 4);
    bf16x4 b0 = *(const bf16x4*)(Yb + (size_t)p0 * DDIM + i * 4);
    bf16x4 a1 = *(const bf16x4*)(Ya + (size_t)p1 * DDIM + i * 4);
    bf16x4 b1 = *(const bf16x4*)(Yb + (size_t)p1 * DDIM + i * 4);
    float4 o;
    o.x = w0 * ((float)a0.x + (float)b0.x) + w1 * ((float)a1.x + (float)b1.x);
    o.y = w0 * ((float)a0.y + (float)b0.y) + w1 * ((float)a1.y + (float)b1.y);
    o.z = w0 * ((float)a0.z + (float)b0.z) + w1 * ((float)a1.z + (float)b1.z);
    o.w = w0 * ((float)a0.w + (float)b0.w) + w1 * ((float)a1.w + (float)b1.w);
    *(float4*)(out + (size_t)t * DDIM + i * 4) = o;
}

extern "C" void kernel_launch(void* const* d_in, const int* in_sizes, int n_in,
                              void* d_out, int out_size, void* d_ws, size_t ws_size,
                              hipStream_t stream) {
    const float* x      = (const float*)d_in[0];
    const float* gate_w = (const float*)d_in[1];
    const float* ebias  = (const float*)d_in[2];
    const float* wgp    = (const float*)d_in[3];
    const float* wup    = (const float*)d_in[4];
    const float* wdp    = (const float*)d_in[5];
    float* out = (float*)d_out;

    int*   ctrl     = (int*)d_ws;                          // 128 ints
    int*   tok_e    = ctrl + 128;                          // 2T
    float* tok_w    = (float*)(tok_e + 2 * T_TOK);         // 2T
    int*   pair_tok = (int*)(tok_w + 2 * T_TOK);           // RMAX
    int*   tok_pos  = pair_tok + RMAX;                     // 2T
    bf16*  Xg       = (bf16*)(tok_pos + 2 * T_TOK);        // RMAX*768 (reused as Ya)
    bf16*  Ya       = Xg;
    bf16*  Yb       = Xg + (size_t)RMAX * DDIM;            // RMAX*768
    bf16*  G        = Yb + (size_t)RMAX * DDIM;            // RMAX*2688
    bf16*  WgT      = G + (size_t)RMAX * HDIM;
    bf16*  WuT      = WgT + (size_t)NEXP * DDIM * HDIM;
    bf16*  WdT      = WuT + (size_t)NEXP * DDIM * HDIM;

    hipMemsetAsync(out + (size_t)T_TOK * DDIM, 0, sizeof(float), stream);  // z_loss
    hipMemsetAsync(d_ws, 0, 512, stream);                                  // ctrl

    router_kernel<<<T_TOK / 4, 256, 0, stream>>>(x, gate_w, ebias, ctrl, tok_e, tok_w,
                                                 out + (size_t)T_TOK * DDIM);
    offsets_kernel<<<1, 64, 0, stream>>>(ctrl);
    scatter_kernel<<<T_TOK / 256, 256, 0, stream>>>(ctrl, tok_e, tok_w, pair_tok, tok_pos);
    transpose_kernel<<<dim3(504, 24), 256, 0, stream>>>(wgp, wup, wdp, WgT, WuT, WdT);
    gather_kernel<<<RMAX, 192, 0, stream>>>(x, ctrl, pair_tok, Xg);
    gemm1_kernel<<<NMT * NT1, 256, 0, stream>>>(Xg, WgT, WuT, ctrl, G);
    gemm2_kernel<<<NMT * NT2 * 2, 256, 0, stream>>>(G, WdT, ctrl, Ya, Yb);
    combine_kernel<<<T_TOK, 192, 0, stream>>>(Ya, Yb, tok_pos, tok_w, out);
}